// Round 4
// baseline (72.286 us; speedup 1.0000x reference)
//
#include <hip/hip_runtime.h>
#include <hip/hip_cooperative_groups.h>

namespace cg = cooperative_groups;

#define T_LEN 16384
#define B_N   128
#define S_N   31
#define M_SH  15
#define NCHUNK 8
#define TCHUNK (T_LEN / NCHUNK)   // 2048
#define BLOCK  256
#define VT     8
#define NBLOCKS (B_N * NCHUNK)    // 1024 = 4 blocks/CU on 256 CUs
#define HALO   16
#define TILE_F4 ((TCHUNK + 2 * HALO) / 4)   // 520

// XOR swizzle at float4 granularity: spreads the 32B-strided window reads
// across banks (worst case 2 lanes/bank = free). Bijective within 128B groups.
__device__ __forceinline__ int swz(int f4) { return f4 ^ ((f4 >> 3) & 7); }

// __launch_bounds__(256, 4): 4 waves/SIMD -> VGPR<=128 -> 4 blocks/CU
// guaranteed co-resident (16 waves/CU, ~34KB LDS/CU) so the cooperative
// launch of 1024 blocks cannot fail occupancy.
__global__ __launch_bounds__(BLOCK, 4) void talos_coop(
    const float* __restrict__ y_pred,
    const float* __restrict__ y_true,
    const float* __restrict__ theta,
    const int* __restrict__ pidx,
    float* __restrict__ partial,
    float* __restrict__ out) {

  cg::grid_group grid = cg::this_grid();

  __shared__ float tile[TILE_F4 * 4];          // 8320 B, swizzled
  __shared__ float wsh[S_N];
  __shared__ float redL[BLOCK / 64];

  const int bid   = blockIdx.x;
  const int b     = bid / NCHUNK;
  const int chunk = bid % NCHUNK;
  const int t0    = chunk * TCHUNK;
  const int tid   = threadIdx.x;
  const float* yt_b = y_true + b * T_LEN;
  const float* yp_b = y_pred + b * T_LEN;

  // ---- stage y_true chunk + halo into swizzled LDS (float4, zero-padded) ----
  for (int f = tid; f < TILE_F4; f += BLOCK) {
    int g = t0 - HALO + f * 4;                 // 16B-aligned global float index
    float4 v;
    if (g >= 0 && g + 3 < T_LEN) {
      v = *(const float4*)(yt_b + g);
    } else {
      v.x = (g + 0 >= 0 && g + 0 < T_LEN) ? yt_b[g + 0] : 0.f;
      v.y = (g + 1 >= 0 && g + 1 < T_LEN) ? yt_b[g + 1] : 0.f;
      v.z = (g + 2 >= 0 && g + 2 < T_LEN) ? yt_b[g + 2] : 0.f;
      v.w = (g + 3 >= 0 && g + 3 < T_LEN) ? yt_b[g + 3] : 0.f;
    }
    *(float4*)&tile[swz(f) * 4] = v;
  }

  // ---- softmax weights for this b (wave 0, lanes 0..31) ----
  if (tid < 32) {
    float v = (tid < S_N) ? theta[pidx[b] * S_N + tid] : -1e30f;
    float m = v;
#pragma unroll
    for (int off = 16; off; off >>= 1) m = fmaxf(m, __shfl_xor(m, off, 32));
    float e = (tid < S_N) ? __expf(v - m) : 0.f;
    float s = e;
#pragma unroll
    for (int off = 16; off; off >>= 1) s += __shfl_xor(s, off, 32);
    if (tid < S_N) wsh[tid] = e / s;
  }
  __syncthreads();

  // ---- register-blocked weighted 31-tap convolution over VT=8 elements ----
  const int lt0 = tid * VT;
  float yp[VT];
  *(float4*)&yp[0] = *(const float4*)(yp_b + t0 + lt0);
  *(float4*)&yp[4] = *(const float4*)(yp_b + t0 + lt0 + 4);

  float win[VT + 2 * HALO];                    // 40 floats: yt[t0+lt0-16 .. +23]
#pragma unroll
  for (int q = 0; q < (VT + 2 * HALO) / 4; ++q) {
    int f4 = (lt0 >> 2) + q;                   // 2*tid + q
    *(float4*)&win[q * 4] = *(const float4*)&tile[swz(f4) * 4];
  }

  float lin[VT];
#pragma unroll
  for (int j = 0; j < VT; ++j) lin[j] = 0.f;
#pragma unroll
  for (int s = 0; s < S_N; ++s) {
    const float ws = wsh[s];                   // LDS broadcast, keeps VGPR<=128
#pragma unroll
    for (int j = 0; j < VT; ++j)
      lin[j] = fmaf(ws, win[j + s + 1], lin[j]);   // lin[t] = sum_s w_s*yt[t+s-15]
  }

  // acc = sum (yp^2 - 2*yp*lin) + sum yt^2   (weighted yt^2 term collapses
  // to unweighted per-chunk sum since sum_s w_s = 1; edges fixed below)
  float acc = 0.f;
#pragma unroll
  for (int j = 0; j < VT; ++j) {
    acc = fmaf(yp[j], fmaf(-2.f, lin[j], yp[j]), acc);
    float a = win[HALO + j];
    acc = fmaf(a, a, acc);
  }

  // ---- zero-pad edge corrections, wave-parallel (validated in R3) ----
  // chunk 0:  corr = sum_{j=0..14} yt[j]^2 * sum_{k>j} wsh[k+15]
  if (chunk == 0 && tid < M_SH) {
    float a = yt_b[tid];
    float tw = 0.f;
#pragma unroll
    for (int k = 1; k <= M_SH; ++k) if (k > tid) tw += wsh[k + M_SH];
    acc -= a * a * tw;
  }
  // chunk 7:  corr = sum_{i=1..15} yt[T-i]^2 * sum_{k>=i} wsh[15-k]
  if (chunk == NCHUNK - 1 && tid < M_SH) {
    const int j = tid + 1;
    float z = yt_b[T_LEN - j];
    float tw = 0.f;
#pragma unroll
    for (int k = 1; k <= M_SH; ++k) if (k >= j) tw += wsh[M_SH - k];
    acc -= z * z * tw;
  }

  // ---- block reduce -> partial[bid] ----
#pragma unroll
  for (int off = 32; off; off >>= 1) acc += __shfl_down(acc, off, 64);
  const int lane = tid & 63, wv = tid >> 6;
  if (lane == 0) redL[wv] = acc;
  __syncthreads();
  if (tid == 0) {
    float P = 0.f;
#pragma unroll
    for (int i = 0; i < BLOCK / 64; ++i) P += redL[i];
    partial[bid] = P;
  }

  // ---- grid-wide barrier (runtime-managed, deterministic) ----
  grid.sync();

  // ---- block 0: fixed-order final reduction ----
  if (bid == 0) {
    double a = 0.0;
    for (int i = tid; i < NBLOCKS; i += BLOCK) a += (double)partial[i];
#pragma unroll
    for (int off = 32; off; off >>= 1) a += __shfl_down(a, off, 64);
    __shared__ double redD[BLOCK / 64];
    if (lane == 0) redD[wv] = a;
    __syncthreads();
    if (tid == 0) {
      double tot = 0.0;
#pragma unroll
      for (int i = 0; i < BLOCK / 64; ++i) tot += redD[i];
      out[0] = (float)(tot / ((double)T_LEN * (double)B_N));
    }
  }
}

extern "C" void kernel_launch(void* const* d_in, const int* in_sizes, int n_in,
                              void* d_out, int out_size, void* d_ws, size_t ws_size,
                              hipStream_t stream) {
  const float* y_pred = (const float*)d_in[0];
  const float* y_true = (const float*)d_in[1];
  const float* theta  = (const float*)d_in[2];
  const int*   pidx   = (const int*)d_in[3];
  float* out = (float*)d_out;
  float* partial = (float*)d_ws;               // NBLOCKS floats

  void* args[] = { (void*)&y_pred, (void*)&y_true, (void*)&theta, (void*)&pidx,
                   (void*)&partial, (void*)&out };
  hipLaunchCooperativeKernel((void*)talos_coop, dim3(NBLOCKS), dim3(BLOCK),
                             args, 0, stream);
}

// Round 5
// 36.639 us; speedup vs baseline: 1.9729x; 1.9729x over previous
//
#include <hip/hip_runtime.h>
#include <math.h>

#define T_LEN 16384
#define B_N   128
#define S_N   31
#define M_SH  15
#define NCHUNK 8
#define TCHUNK (T_LEN / NCHUNK)   // 2048
#define BLOCK  256
#define VT     8
#define NBLOCKS (B_N * NCHUNK)    // 1024
#define HALO   16
#define TILE_F4 ((TCHUNK + 2 * HALO) / 4)   // 520

// XOR swizzle at float4 granularity: spreads the 32B-strided window reads
// across banks (worst case 2-way = free). Bijective within 128B groups.
__device__ __forceinline__ int swz(int f4) { return f4 ^ ((f4 >> 3) & 7); }

__global__ __launch_bounds__(BLOCK) void talos_single(
    const float* __restrict__ y_pred,
    const float* __restrict__ y_true,
    const float* __restrict__ theta,
    const int* __restrict__ pidx,
    float* __restrict__ partial,
    unsigned int* __restrict__ ticket,
    float* __restrict__ out) {

  __shared__ float tile[TILE_F4 * 4];          // 8320 B, swizzled
  __shared__ float wsh[S_N];
  __shared__ float redL[BLOCK / 64];
  __shared__ int   is_last;

  const int bid   = blockIdx.x;
  const int b     = bid / NCHUNK;
  const int chunk = bid % NCHUNK;
  const int t0    = chunk * TCHUNK;
  const int tid   = threadIdx.x;
  const float* yt_b = y_true + b * T_LEN;
  const float* yp_b = y_pred + b * T_LEN;

  // ---- stage y_true chunk + halo into swizzled LDS (float4, zero-padded) ----
  for (int f = tid; f < TILE_F4; f += BLOCK) {
    int g = t0 - HALO + f * 4;                 // 16B-aligned global float index
    float4 v;
    if (g >= 0 && g + 3 < T_LEN) {
      v = *(const float4*)(yt_b + g);
    } else {
      v.x = (g + 0 >= 0 && g + 0 < T_LEN) ? yt_b[g + 0] : 0.f;
      v.y = (g + 1 >= 0 && g + 1 < T_LEN) ? yt_b[g + 1] : 0.f;
      v.z = (g + 2 >= 0 && g + 2 < T_LEN) ? yt_b[g + 2] : 0.f;
      v.w = (g + 3 >= 0 && g + 3 < T_LEN) ? yt_b[g + 3] : 0.f;
    }
    *(float4*)&tile[swz(f) * 4] = v;
  }

  // ---- softmax weights for this b (wave 0, lanes 0..31) ----
  if (tid < 32) {
    float v = (tid < S_N) ? theta[pidx[b] * S_N + tid] : -1e30f;
    float m = v;
#pragma unroll
    for (int off = 16; off; off >>= 1) m = fmaxf(m, __shfl_xor(m, off, 32));
    float e = (tid < S_N) ? __expf(v - m) : 0.f;
    float s = e;
#pragma unroll
    for (int off = 16; off; off >>= 1) s += __shfl_xor(s, off, 32);
    if (tid < S_N) wsh[tid] = e / s;
  }
  __syncthreads();

  // ---- register-blocked weighted 31-tap convolution over VT=8 elements ----
  const int lt0 = tid * VT;
  float yp[VT];
  *(float4*)&yp[0] = *(const float4*)(yp_b + t0 + lt0);
  *(float4*)&yp[4] = *(const float4*)(yp_b + t0 + lt0 + 4);

  float win[VT + 2 * HALO];                    // 40 floats: yt[t0+lt0-16 .. +23]
#pragma unroll
  for (int q = 0; q < (VT + 2 * HALO) / 4; ++q) {
    int f4 = (lt0 >> 2) + q;                   // 2*tid + q
    *(float4*)&win[q * 4] = *(const float4*)&tile[swz(f4) * 4];
  }

  float lin[VT];
#pragma unroll
  for (int j = 0; j < VT; ++j) lin[j] = 0.f;
#pragma unroll
  for (int s = 0; s < S_N; ++s) {
    const float ws = wsh[s];                   // LDS broadcast (no conflict)
#pragma unroll
    for (int j = 0; j < VT; ++j)
      lin[j] = fmaf(ws, win[j + s + 1], lin[j]);   // lin[t] = sum_s w_s*yt[t+s-15]
  }

  // acc = sum (yp^2 - 2*yp*lin) + sum yt^2   (weighted yt^2 collapses to the
  // unweighted per-chunk sum since sum_s w_s = 1; edges corrected below)
  float acc = 0.f;
#pragma unroll
  for (int j = 0; j < VT; ++j) {
    acc = fmaf(yp[j], fmaf(-2.f, lin[j], yp[j]), acc);
    float a = win[HALO + j];
    acc = fmaf(a, a, acc);
  }

  // ---- zero-pad edge corrections, wave-parallel (verified absmax=0 in R4) ----
  if (chunk == 0 && tid < M_SH) {
    float a = yt_b[tid];
    float tw = 0.f;
#pragma unroll
    for (int k = 1; k <= M_SH; ++k) if (k > tid) tw += wsh[k + M_SH];
    acc -= a * a * tw;
  }
  if (chunk == NCHUNK - 1 && tid < M_SH) {
    const int j = tid + 1;
    float z = yt_b[T_LEN - j];
    float tw = 0.f;
#pragma unroll
    for (int k = 1; k <= M_SH; ++k) if (k >= j) tw += wsh[M_SH - k];
    acc -= z * z * tw;
  }

  // ---- block reduce -> partial[bid] ----
#pragma unroll
  for (int off = 32; off; off >>= 1) acc += __shfl_down(acc, off, 64);
  const int lane = tid & 63, wv = tid >> 6;
  if (lane == 0) redL[wv] = acc;
  __syncthreads();

  if (tid == 0) {
    float P = 0.f;
#pragma unroll
    for (int i = 0; i < BLOCK / 64; ++i) P += redL[i];
    // Release-store partial at agent scope, then take a ticket.
    __hip_atomic_store(&partial[bid], P, __ATOMIC_RELEASE,
                       __HIP_MEMORY_SCOPE_AGENT);
    unsigned int t = __hip_atomic_fetch_add(ticket, 1u, __ATOMIC_ACQ_REL,
                                            __HIP_MEMORY_SCOPE_AGENT);
    // Modulo trick: any 1024 consecutive tickets contain exactly one value
    // == 1023 (mod 1024) -> works with arbitrary initial ticket contents
    // (0xAA poison, accumulation across graph replays). No reset needed.
    is_last = (((t + 1u) & (unsigned)(NBLOCKS - 1)) == 0u);
  }
  __syncthreads();

  // ---- last-arriving block: fixed-order final reduction (deterministic) ----
  if (is_last) {
    double a = 0.0;
    for (int i = tid; i < NBLOCKS; i += BLOCK)
      a += (double)__hip_atomic_load(&partial[i], __ATOMIC_RELAXED,
                                     __HIP_MEMORY_SCOPE_AGENT);
#pragma unroll
    for (int off = 32; off; off >>= 1) a += __shfl_down(a, off, 64);
    __shared__ double redD[BLOCK / 64];
    if (lane == 0) redD[wv] = a;
    __syncthreads();
    if (tid == 0) {
      double tot = 0.0;
#pragma unroll
      for (int i = 0; i < BLOCK / 64; ++i) tot += redD[i];
      out[0] = (float)(tot / ((double)T_LEN * (double)B_N));
    }
  }
}

extern "C" void kernel_launch(void* const* d_in, const int* in_sizes, int n_in,
                              void* d_out, int out_size, void* d_ws, size_t ws_size,
                              hipStream_t stream) {
  const float* y_pred = (const float*)d_in[0];
  const float* y_true = (const float*)d_in[1];
  const float* theta  = (const float*)d_in[2];
  const int*   pidx   = (const int*)d_in[3];
  float* out = (float*)d_out;

  float*        partial = (float*)d_ws;                     // 1024 floats
  unsigned int* ticket  = (unsigned int*)((char*)d_ws + 4096);

  talos_single<<<NBLOCKS, BLOCK, 0, stream>>>(y_pred, y_true, theta, pidx,
                                              partial, ticket, out);
}

// Round 6
// 11.612 us; speedup vs baseline: 6.2249x; 3.1551x over previous
//
#include <hip/hip_runtime.h>

#define T_LEN 16384
#define B_N   128
#define S_N   31
#define M_SH  15
#define NCHUNK 8
#define TCHUNK (T_LEN / NCHUNK)   // 2048
#define BLOCK  256
#define VT     8
#define NBLOCKS (B_N * NCHUNK)    // 1024
#define HALO   16
#define TILE_F4 ((TCHUNK + 2 * HALO) / 4)   // 520

// XOR swizzle at float4 granularity: spreads the 32B-strided window reads
// across banks (worst case 2-way = free). Bijective within 128B groups.
__device__ __forceinline__ int swz(int f4) { return f4 ^ ((f4 >> 3) & 7); }

__global__ __launch_bounds__(BLOCK) void talos_main(
    const float* __restrict__ y_pred,
    const float* __restrict__ y_true,
    const float* __restrict__ theta,
    const int* __restrict__ pidx,
    float* __restrict__ partial) {

  __shared__ float tile[TILE_F4 * 4];          // 8320 B, swizzled
  __shared__ float wsh[S_N];
  __shared__ float redL[BLOCK / 64];

  const int bid   = blockIdx.x;
  const int b     = bid / NCHUNK;
  const int chunk = bid % NCHUNK;
  const int t0    = chunk * TCHUNK;
  const int tid   = threadIdx.x;
  const float* yt_b = y_true + b * T_LEN;
  const float* yp_b = y_pred + b * T_LEN;

  // ---- stage y_true chunk + halo into swizzled LDS (float4, zero-padded) ----
  for (int f = tid; f < TILE_F4; f += BLOCK) {
    int g = t0 - HALO + f * 4;                 // 16B-aligned global float index
    float4 v;
    if (g >= 0 && g + 3 < T_LEN) {
      v = *(const float4*)(yt_b + g);
    } else {
      v.x = (g + 0 >= 0 && g + 0 < T_LEN) ? yt_b[g + 0] : 0.f;
      v.y = (g + 1 >= 0 && g + 1 < T_LEN) ? yt_b[g + 1] : 0.f;
      v.z = (g + 2 >= 0 && g + 2 < T_LEN) ? yt_b[g + 2] : 0.f;
      v.w = (g + 3 >= 0 && g + 3 < T_LEN) ? yt_b[g + 3] : 0.f;
    }
    *(float4*)&tile[swz(f) * 4] = v;
  }

  // ---- softmax weights for this b (wave 0, lanes 0..31) ----
  if (tid < 32) {
    float v = (tid < S_N) ? theta[pidx[b] * S_N + tid] : -1e30f;
    float m = v;
#pragma unroll
    for (int off = 16; off; off >>= 1) m = fmaxf(m, __shfl_xor(m, off, 32));
    float e = (tid < S_N) ? __expf(v - m) : 0.f;
    float s = e;
#pragma unroll
    for (int off = 16; off; off >>= 1) s += __shfl_xor(s, off, 32);
    if (tid < S_N) wsh[tid] = e / s;
  }
  __syncthreads();

  // ---- register-blocked weighted 31-tap convolution over VT=8 elements ----
  const int lt0 = tid * VT;
  float yp[VT];
  *(float4*)&yp[0] = *(const float4*)(yp_b + t0 + lt0);
  *(float4*)&yp[4] = *(const float4*)(yp_b + t0 + lt0 + 4);

  float win[VT + 2 * HALO];                    // 40 floats: yt[t0+lt0-16 .. +23]
#pragma unroll
  for (int q = 0; q < (VT + 2 * HALO) / 4; ++q) {
    int f4 = (lt0 >> 2) + q;                   // 2*tid + q
    *(float4*)&win[q * 4] = *(const float4*)&tile[swz(f4) * 4];
  }

  float lin[VT];
#pragma unroll
  for (int j = 0; j < VT; ++j) lin[j] = 0.f;
#pragma unroll
  for (int s = 0; s < S_N; ++s) {
    const float ws = wsh[s];                   // LDS broadcast (no conflict)
#pragma unroll
    for (int j = 0; j < VT; ++j)
      lin[j] = fmaf(ws, win[j + s + 1], lin[j]);   // lin[t] = sum_s w_s*yt[t+s-15]
  }

  // acc = sum (yp^2 - 2*yp*lin) + sum yt^2   (weighted yt^2 collapses to the
  // unweighted per-chunk sum since sum_s w_s = 1; edges corrected below)
  float acc = 0.f;
#pragma unroll
  for (int j = 0; j < VT; ++j) {
    acc = fmaf(yp[j], fmaf(-2.f, lin[j], yp[j]), acc);
    float a = win[HALO + j];
    acc = fmaf(a, a, acc);
  }

  // ---- zero-pad edge corrections, wave-parallel (verified absmax=0, R4/R5) ----
  if (chunk == 0 && tid < M_SH) {
    float a = yt_b[tid];
    float tw = 0.f;
#pragma unroll
    for (int k = 1; k <= M_SH; ++k) if (k > tid) tw += wsh[k + M_SH];
    acc -= a * a * tw;
  }
  if (chunk == NCHUNK - 1 && tid < M_SH) {
    const int j = tid + 1;
    float z = yt_b[T_LEN - j];
    float tw = 0.f;
#pragma unroll
    for (int k = 1; k <= M_SH; ++k) if (k >= j) tw += wsh[M_SH - k];
    acc -= z * z * tw;
  }

  // ---- block reduce -> partial[bid] (plain store; kernel boundary = release) ----
#pragma unroll
  for (int off = 32; off; off >>= 1) acc += __shfl_down(acc, off, 64);
  const int lane = tid & 63, wv = tid >> 6;
  if (lane == 0) redL[wv] = acc;
  __syncthreads();
  if (tid == 0) {
    float P = 0.f;
#pragma unroll
    for (int i = 0; i < BLOCK / 64; ++i) P += redL[i];
    partial[bid] = P;
  }
}

// Minimal tail: 1 block, one float4 per thread, fixed-order double reduce.
__global__ __launch_bounds__(BLOCK) void talos_tail(
    const float* __restrict__ partial, float* __restrict__ out) {
  __shared__ double redD[BLOCK / 64];
  const int tid = threadIdx.x;
  float4 v = *(const float4*)(partial + tid * 4);     // 256 * 4 = 1024
  double a = (double)v.x + (double)v.y + (double)v.z + (double)v.w;
#pragma unroll
  for (int off = 32; off; off >>= 1) a += __shfl_down(a, off, 64);
  const int lane = tid & 63, wv = tid >> 6;
  if (lane == 0) redD[wv] = a;
  __syncthreads();
  if (tid == 0) {
    double tot = 0.0;
#pragma unroll
    for (int i = 0; i < BLOCK / 64; ++i) tot += redD[i];
    out[0] = (float)(tot / ((double)T_LEN * (double)B_N));
  }
}

extern "C" void kernel_launch(void* const* d_in, const int* in_sizes, int n_in,
                              void* d_out, int out_size, void* d_ws, size_t ws_size,
                              hipStream_t stream) {
  const float* y_pred = (const float*)d_in[0];
  const float* y_true = (const float*)d_in[1];
  const float* theta  = (const float*)d_in[2];
  const int*   pidx   = (const int*)d_in[3];
  float* out = (float*)d_out;
  float* partial = (float*)d_ws;               // 1024 floats

  talos_main<<<NBLOCKS, BLOCK, 0, stream>>>(y_pred, y_true, theta, pidx, partial);
  talos_tail<<<1, BLOCK, 0, stream>>>(partial, out);
}